// Round 1
// baseline (1035.240 us; speedup 1.0000x reference)
//
#include <hip/hip_runtime.h>
#include <math.h>

#define L_SEQ 2048
#define DM 1024
#define DI 2048
#define DS 16
#define DTR 64
#define EPS 1e-5f

// ---------------- LayerNorm ----------------
__global__ __launch_bounds__(256) void ln_kernel(const float* __restrict__ x,
                                                 const float* __restrict__ sc,
                                                 const float* __restrict__ bi,
                                                 float* __restrict__ xn) {
  int row = blockIdx.x;
  int t = threadIdx.x;
  float4 xv = ((const float4*)(x + (size_t)row * DM))[t];
  float s  = xv.x + xv.y + xv.z + xv.w;
  float s2 = xv.x*xv.x + xv.y*xv.y + xv.z*xv.z + xv.w*xv.w;
  #pragma unroll
  for (int m = 32; m >= 1; m >>= 1) {
    s  += __shfl_xor(s, m);
    s2 += __shfl_xor(s2, m);
  }
  __shared__ float red[8];
  int wid = t >> 6, lane = t & 63;
  if (lane == 0) { red[wid] = s; red[4 + wid] = s2; }
  __syncthreads();
  s  = red[0] + red[1] + red[2] + red[3];
  s2 = red[4] + red[5] + red[6] + red[7];
  float mu = s * (1.f / DM);
  float var = s2 * (1.f / DM) - mu * mu;
  float rs = rsqrtf(var + EPS);
  float4 sc4 = ((const float4*)sc)[t];
  float4 bi4 = ((const float4*)bi)[t];
  float4 o;
  o.x = (xv.x - mu) * rs * sc4.x + bi4.x;
  o.y = (xv.y - mu) * rs * sc4.y + bi4.y;
  o.z = (xv.z - mu) * rs * sc4.z + bi4.z;
  o.w = (xv.w - mu) * rs * sc4.w + bi4.w;
  ((float4*)(xn + (size_t)row * DM))[t] = o;
}

// ---------------- Generic fp32 GEMM: C = A(MxK) @ B(KxN), row-major ----------------
// BM=128, BN=64, BK=16; 256 threads; 8x4 acc per thread.
// EPI: 0 = none, 1 = softplus(acc + bias[col]), 2 = acc + R[row,col]
template<int EPI>
__global__ __launch_bounds__(256) void gemm_f32(
    const float* __restrict__ A, int lda,
    const float* __restrict__ B, int ldb,
    float* __restrict__ C, int ldc,
    int M, int N, int K,
    const float* __restrict__ bias,
    const float* __restrict__ R, int ldr)
{
  __shared__ __align__(16) float As[16][132];  // [k][m], padded
  __shared__ __align__(16) float Bs[16][64];   // [k][n]
  int tid = threadIdx.x;
  int tx = tid & 15, ty = tid >> 4;
  int m0 = blockIdx.y * 128, n0 = blockIdx.x * 64;
  float acc[8][4];
  #pragma unroll
  for (int i = 0; i < 8; ++i)
    #pragma unroll
    for (int j = 0; j < 4; ++j) acc[i][j] = 0.f;

  for (int k0 = 0; k0 < K; k0 += 16) {
    int kk4 = (tid & 3) << 2;
    #pragma unroll
    for (int p = 0; p < 2; ++p) {
      int r = (tid >> 2) + 64 * p;
      float4 av = *(const float4*)&A[(size_t)(m0 + r) * lda + k0 + kk4];
      As[kk4 + 0][r] = av.x;
      As[kk4 + 1][r] = av.y;
      As[kk4 + 2][r] = av.z;
      As[kk4 + 3][r] = av.w;
    }
    int rb = tid >> 4;
    int c4 = (tid & 15) << 2;
    *(float4*)&Bs[rb][c4] = *(const float4*)&B[(size_t)(k0 + rb) * ldb + n0 + c4];
    __syncthreads();
    #pragma unroll
    for (int kk = 0; kk < 16; ++kk) {
      float4 a0 = *(const float4*)&As[kk][ty * 8];
      float4 a1 = *(const float4*)&As[kk][ty * 8 + 4];
      float4 b  = *(const float4*)&Bs[kk][tx * 4];
      float av[8] = {a0.x, a0.y, a0.z, a0.w, a1.x, a1.y, a1.z, a1.w};
      float bv[4] = {b.x, b.y, b.z, b.w};
      #pragma unroll
      for (int i = 0; i < 8; ++i)
        #pragma unroll
        for (int j = 0; j < 4; ++j) acc[i][j] += av[i] * bv[j];
    }
    __syncthreads();
  }

  #pragma unroll
  for (int i = 0; i < 8; ++i) {
    int row = m0 + ty * 8 + i;
    int col = n0 + tx * 4;
    float4 o;
    float v[4];
    #pragma unroll
    for (int j = 0; j < 4; ++j) v[j] = acc[i][j];
    if (EPI == 1) {
      #pragma unroll
      for (int j = 0; j < 4; ++j) {
        float w = v[j] + bias[col + j];
        v[j] = (w > 20.f) ? w : log1pf(__expf(w));
      }
    }
    if (EPI == 2) {
      float4 r4 = *(const float4*)&R[(size_t)row * ldr + col];
      v[0] += r4.x; v[1] += r4.y; v[2] += r4.z; v[3] += r4.w;
    }
    o.x = v[0]; o.y = v[1]; o.z = v[2]; o.w = v[3];
    *(float4*)&C[(size_t)row * ldc + col] = o;
  }
}

// ---------------- causal conv4 + SiLU ----------------
__global__ __launch_bounds__(256) void conv_silu_kernel(
    const float* __restrict__ xr,  // u = xr[:, :DI], row stride 2*DI
    const float* __restrict__ Wc, const float* __restrict__ bc,
    float* __restrict__ u2)
{
  int d = blockIdx.x * 256 + threadIdx.x;
  int l = blockIdx.y;
  float acc = bc[d];
  #pragma unroll
  for (int k = 0; k < 4; ++k) {
    int ll = l + k - 3;
    if (ll >= 0) acc += xr[(size_t)ll * (2 * DI) + d] * Wc[k * DI + d];
  }
  float sig = 1.f / (1.f + __expf(-acc));
  u2[(size_t)l * DI + d] = acc * sig;
}

// ---------------- x_dbl = u2 @ W_x (K=2048, N=96) ----------------
__global__ __launch_bounds__(128) void xdbl_kernel(
    const float* __restrict__ u2, const float* __restrict__ Wx,
    float* __restrict__ xdbl)
{
  __shared__ float srow[DI];
  int l = blockIdx.x;
  for (int i = threadIdx.x; i < DI / 4; i += 128)
    ((float4*)srow)[i] = ((const float4*)(u2 + (size_t)l * DI))[i];
  __syncthreads();
  int j = threadIdx.x;
  if (j < 96) {
    float acc = 0.f;
    #pragma unroll 8
    for (int k = 0; k < DI; ++k) acc += srow[k] * Wx[k * 96 + j];
    xdbl[(size_t)l * 96 + j] = acc;
  }
}

// ---------------- selective scan ----------------
// block = 64 threads = 4 channels x 16 states; grid = DI/4 = 512
#define CHUNK 64
__global__ __launch_bounds__(64) void scan_kernel(
    const float* __restrict__ delta, const float* __restrict__ u2,
    const float* __restrict__ res, int ldres,
    const float* __restrict__ xdbl,
    const float* __restrict__ A_log, const float* __restrict__ Dp,
    float* __restrict__ y, int ldy)
{
  int t = threadIdx.x;
  int ch = t >> 4;
  int n  = t & 15;
  int d0 = blockIdx.x * 4;
  int d  = d0 + ch;

  __shared__ __align__(16) float sd[CHUNK][4], su[CHUNK][4], sr[CHUNK][4];
  __shared__ __align__(16) float sB[CHUNK][16], sC[CHUNK][16];
  __shared__ __align__(16) float sy[CHUNK][4];

  float An = -__expf(A_log[d * DS + n]);
  float Dd = Dp[d];
  float h = 0.f;

  float4 rd, ru, rr, rB[4], rC[4];
  auto LOAD = [&](int c0) {
    int l = c0 + t;
    rd = *(const float4*)&delta[(size_t)l * DI + d0];
    ru = *(const float4*)&u2[(size_t)l * DI + d0];
    rr = *(const float4*)&res[(size_t)l * ldres + d0];
    #pragma unroll
    for (int r = 0; r < 4; ++r) {
      int ll = c0 + (t >> 2) + r * 16;
      int n4 = (t & 3) * 4;
      rB[r] = *(const float4*)&xdbl[(size_t)ll * 96 + 64 + n4];
      rC[r] = *(const float4*)&xdbl[(size_t)ll * 96 + 80 + n4];
    }
  };

  LOAD(0);
  for (int c0 = 0; c0 < L_SEQ; c0 += CHUNK) {
    __syncthreads();  // guard LDS overwrite vs previous compute
    *(float4*)sd[t] = rd;
    *(float4*)su[t] = ru;
    *(float4*)sr[t] = rr;
    #pragma unroll
    for (int r = 0; r < 4; ++r) {
      *(float4*)&sB[(t >> 2) + r * 16][(t & 3) * 4] = rB[r];
      *(float4*)&sC[(t >> 2) + r * 16][(t & 3) * 4] = rC[r];
    }
    if (c0 + CHUNK < L_SEQ) LOAD(c0 + CHUNK);  // prefetch next chunk into regs
    __syncthreads();

    for (int ll = 0; ll < CHUNK; ++ll) {
      float dl = sd[ll][ch];
      float ul = su[ll][ch];
      float Bn = sB[ll][n];
      float Cn = sC[ll][n];
      float dA = __expf(dl * An);
      h = dA * h + dl * ul * Bn;
      float v = h * Cn;
      v += __shfl_xor(v, 1);
      v += __shfl_xor(v, 2);
      v += __shfl_xor(v, 4);
      v += __shfl_xor(v, 8);
      if (n == 0) {
        float yv = v + ul * Dd;
        float rv = sr[ll][ch];
        float sig = 1.f / (1.f + __expf(-rv));
        sy[ll][ch] = yv * rv * sig;
      }
    }
    __syncthreads();
    *(float4*)&y[(size_t)(c0 + t) * ldy + d0] = *(float4*)sy[t];
  }
}

// ---------------- launch ----------------
extern "C" void kernel_launch(void* const* d_in, const int* in_sizes, int n_in,
                              void* d_out, int out_size, void* d_ws, size_t ws_size,
                              hipStream_t stream)
{
  const float* x      = (const float*)d_in[0];
  const float* W_in   = (const float*)d_in[1];
  const float* W_conv = (const float*)d_in[2];
  const float* b_conv = (const float*)d_in[3];
  const float* W_x    = (const float*)d_in[4];
  const float* W_dt   = (const float*)d_in[5];
  const float* b_dt   = (const float*)d_in[6];
  const float* A_log  = (const float*)d_in[7];
  const float* Dp     = (const float*)d_in[8];
  const float* W_out  = (const float*)d_in[9];
  const float* ln_s   = (const float*)d_in[10];
  const float* ln_b   = (const float*)d_in[11];

  char* ws = (char*)d_ws;
  float* xn    = (float*)(ws);                       // 8 MB
  float* xr    = (float*)(ws + (8u  << 20));         // 32 MB: [u | res] per row
  float* u2    = (float*)(ws + (40u << 20));         // 16 MB
  float* xdbl  = (float*)(ws + (56u << 20));         // 0.75 MB
  float* delta = (float*)(ws + (57u << 20));         // 16 MB
  float* res   = xr + DI;                            // ld = 2*DI
  float* y     = xr;                                 // reuse dead u-columns, ld = 2*DI

  ln_kernel<<<L_SEQ, 256, 0, stream>>>(x, ln_s, ln_b, xn);

  gemm_f32<0><<<dim3((2 * DI) / 64, L_SEQ / 128), 256, 0, stream>>>(
      xn, DM, W_in, 2 * DI, xr, 2 * DI, L_SEQ, 2 * DI, DM, nullptr, nullptr, 0);

  conv_silu_kernel<<<dim3(DI / 256, L_SEQ), 256, 0, stream>>>(xr, W_conv, b_conv, u2);

  xdbl_kernel<<<L_SEQ, 128, 0, stream>>>(u2, W_x, xdbl);

  gemm_f32<1><<<dim3(DI / 64, L_SEQ / 128), 256, 0, stream>>>(
      xdbl, 96, W_dt, DI, delta, DI, L_SEQ, DI, DTR, b_dt, nullptr, 0);

  scan_kernel<<<DI / 4, 64, 0, stream>>>(
      delta, u2, res, 2 * DI, xdbl, A_log, Dp, y, 2 * DI);

  gemm_f32<2><<<dim3(DM / 64, L_SEQ / 128), 256, 0, stream>>>(
      y, 2 * DI, W_out, DM, (float*)d_out, DM, L_SEQ, DM, DI, nullptr, x, DM);
}

// Round 2
// 605.452 us; speedup vs baseline: 1.7099x; 1.7099x over previous
//
#include <hip/hip_runtime.h>
#include <math.h>

#define L_SEQ 2048
#define DM 1024
#define DI 2048
#define DS 16
#define DTR 64
#define EPS 1e-5f

// ---------------- LayerNorm ----------------
__global__ __launch_bounds__(256) void ln_kernel(const float* __restrict__ x,
                                                 const float* __restrict__ sc,
                                                 const float* __restrict__ bi,
                                                 float* __restrict__ xn) {
  int row = blockIdx.x;
  int t = threadIdx.x;
  float4 xv = ((const float4*)(x + (size_t)row * DM))[t];
  float s  = xv.x + xv.y + xv.z + xv.w;
  float s2 = xv.x*xv.x + xv.y*xv.y + xv.z*xv.z + xv.w*xv.w;
  #pragma unroll
  for (int m = 32; m >= 1; m >>= 1) {
    s  += __shfl_xor(s, m);
    s2 += __shfl_xor(s2, m);
  }
  __shared__ float red[8];
  int wid = t >> 6, lane = t & 63;
  if (lane == 0) { red[wid] = s; red[4 + wid] = s2; }
  __syncthreads();
  s  = red[0] + red[1] + red[2] + red[3];
  s2 = red[4] + red[5] + red[6] + red[7];
  float mu = s * (1.f / DM);
  float var = s2 * (1.f / DM) - mu * mu;
  float rs = rsqrtf(var + EPS);
  float4 sc4 = ((const float4*)sc)[t];
  float4 bi4 = ((const float4*)bi)[t];
  float4 o;
  o.x = (xv.x - mu) * rs * sc4.x + bi4.x;
  o.y = (xv.y - mu) * rs * sc4.y + bi4.y;
  o.z = (xv.z - mu) * rs * sc4.z + bi4.z;
  o.w = (xv.w - mu) * rs * sc4.w + bi4.w;
  ((float4*)(xn + (size_t)row * DM))[t] = o;
}

// ---------------- Generic fp32 GEMM: C = A(MxK) @ B(KxN), row-major ----------------
// BM=128, BN=64, BK=16; 256 threads; 8x4 acc per thread.
// EPI: 0 = none, 1 = softplus(acc + bias[col]), 2 = acc + R[row,col]
template<int EPI>
__global__ __launch_bounds__(256) void gemm_f32(
    const float* __restrict__ A, int lda,
    const float* __restrict__ B, int ldb,
    float* __restrict__ C, int ldc,
    int M, int N, int K,
    const float* __restrict__ bias,
    const float* __restrict__ R, int ldr)
{
  __shared__ __align__(16) float As[16][132];  // [k][m], padded
  __shared__ __align__(16) float Bs[16][64];   // [k][n]
  int tid = threadIdx.x;
  int tx = tid & 15, ty = tid >> 4;
  int m0 = blockIdx.y * 128, n0 = blockIdx.x * 64;
  float acc[8][4];
  #pragma unroll
  for (int i = 0; i < 8; ++i)
    #pragma unroll
    for (int j = 0; j < 4; ++j) acc[i][j] = 0.f;

  for (int k0 = 0; k0 < K; k0 += 16) {
    int kk4 = (tid & 3) << 2;
    #pragma unroll
    for (int p = 0; p < 2; ++p) {
      int r = (tid >> 2) + 64 * p;
      float4 av = *(const float4*)&A[(size_t)(m0 + r) * lda + k0 + kk4];
      As[kk4 + 0][r] = av.x;
      As[kk4 + 1][r] = av.y;
      As[kk4 + 2][r] = av.z;
      As[kk4 + 3][r] = av.w;
    }
    int rb = tid >> 4;
    int c4 = (tid & 15) << 2;
    *(float4*)&Bs[rb][c4] = *(const float4*)&B[(size_t)(k0 + rb) * ldb + n0 + c4];
    __syncthreads();
    #pragma unroll
    for (int kk = 0; kk < 16; ++kk) {
      float4 a0 = *(const float4*)&As[kk][ty * 8];
      float4 a1 = *(const float4*)&As[kk][ty * 8 + 4];
      float4 b  = *(const float4*)&Bs[kk][tx * 4];
      float av[8] = {a0.x, a0.y, a0.z, a0.w, a1.x, a1.y, a1.z, a1.w};
      float bv[4] = {b.x, b.y, b.z, b.w};
      #pragma unroll
      for (int i = 0; i < 8; ++i)
        #pragma unroll
        for (int j = 0; j < 4; ++j) acc[i][j] += av[i] * bv[j];
    }
    __syncthreads();
  }

  #pragma unroll
  for (int i = 0; i < 8; ++i) {
    int row = m0 + ty * 8 + i;
    int col = n0 + tx * 4;
    float4 o;
    float v[4];
    #pragma unroll
    for (int j = 0; j < 4; ++j) v[j] = acc[i][j];
    if (EPI == 1) {
      #pragma unroll
      for (int j = 0; j < 4; ++j) {
        float w = v[j] + bias[col + j];
        v[j] = (w > 20.f) ? w : log1pf(__expf(w));
      }
    }
    if (EPI == 2) {
      float4 r4 = *(const float4*)&R[(size_t)row * ldr + col];
      v[0] += r4.x; v[1] += r4.y; v[2] += r4.z; v[3] += r4.w;
    }
    o.x = v[0]; o.y = v[1]; o.z = v[2]; o.w = v[3];
    *(float4*)&C[(size_t)row * ldc + col] = o;
  }
}

// ---------------- causal conv4 + SiLU ----------------
__global__ __launch_bounds__(256) void conv_silu_kernel(
    const float* __restrict__ xr,  // u = xr[:, :DI], row stride 2*DI
    const float* __restrict__ Wc, const float* __restrict__ bc,
    float* __restrict__ u2)
{
  int d = blockIdx.x * 256 + threadIdx.x;
  int l = blockIdx.y;
  float acc = bc[d];
  #pragma unroll
  for (int k = 0; k < 4; ++k) {
    int ll = l + k - 3;
    if (ll >= 0) acc += xr[(size_t)ll * (2 * DI) + d] * Wc[k * DI + d];
  }
  float sig = 1.f / (1.f + __expf(-acc));
  u2[(size_t)l * DI + d] = acc * sig;
}

// ---------------- x_dbl = u2 @ W_x (K=2048, N=96) ----------------
__global__ __launch_bounds__(128) void xdbl_kernel(
    const float* __restrict__ u2, const float* __restrict__ Wx,
    float* __restrict__ xdbl)
{
  __shared__ float srow[DI];
  int l = blockIdx.x;
  for (int i = threadIdx.x; i < DI / 4; i += 128)
    ((float4*)srow)[i] = ((const float4*)(u2 + (size_t)l * DI))[i];
  __syncthreads();
  int j = threadIdx.x;
  if (j < 96) {
    float acc = 0.f;
    #pragma unroll 8
    for (int k = 0; k < DI; ++k) acc += srow[k] * Wx[k * 96 + j];
    xdbl[(size_t)l * 96 + j] = acc;
  }
}

// ---------------- selective scan (v2: ILP-restructured) ----------------
// block = 64 threads = 4 channels x 16 states; grid = DI/4 = 512.
// Critical path per step = ONE fma (h = dA*h + dBu). Everything else is
// off-chain: inputs come from transposed LDS staging read as float4 (4 steps
// per ds_read_b128), v=h*C goes to LDS via fire-and-forget ds_write, and the
// 16-state reduction + SiLU gate runs as a fully parallel post-pass.
#define CHUNK 64
__global__ __launch_bounds__(64) void scan_kernel(
    const float* __restrict__ delta, const float* __restrict__ u2,
    const float* __restrict__ res, int ldres,
    const float* __restrict__ xdbl,
    const float* __restrict__ A_log, const float* __restrict__ Dp,
    float* __restrict__ y, int ldy)
{
  int t = threadIdx.x;
  int ch = t >> 4;
  int n  = t & 15;
  int d0 = blockIdx.x * 4;
  int d  = d0 + ch;

  // transposed staging: [ch][ll] / [n][ll], pad 68 to spread banks
  __shared__ __align__(16) float sdT[4][68], suT[4][68];
  __shared__ __align__(16) float sBT[16][68], sCT[16][68];
  __shared__ __align__(16) float srs[CHUNK][4];
  __shared__ __align__(16) float sv[CHUNK][68];   // [ll][ch*16+n]
  __shared__ __align__(16) float sy[CHUNK][4];

  float An = -__expf(A_log[d * DS + n]);
  float Dd = Dp[d];
  float h = 0.f;

  float4 rd, ru, rr, rB[4], rC[4];
  auto LOAD = [&](int c0) {
    int l = c0 + t;
    rd = *(const float4*)&delta[(size_t)l * DI + d0];
    ru = *(const float4*)&u2[(size_t)l * DI + d0];
    rr = *(const float4*)&res[(size_t)l * ldres + d0];
    #pragma unroll
    for (int r = 0; r < 4; ++r) {
      int ll = c0 + (t >> 2) + r * 16;
      int n4 = (t & 3) * 4;
      rB[r] = *(const float4*)&xdbl[(size_t)ll * 96 + 64 + n4];
      rC[r] = *(const float4*)&xdbl[(size_t)ll * 96 + 80 + n4];
    }
  };

  LOAD(0);
  for (int c0 = 0; c0 < L_SEQ; c0 += CHUNK) {
    __syncthreads();  // guard LDS overwrite vs previous chunk's compute
    // --- stage registers -> transposed LDS ---
    sdT[0][t] = rd.x; sdT[1][t] = rd.y; sdT[2][t] = rd.z; sdT[3][t] = rd.w;
    suT[0][t] = ru.x; suT[1][t] = ru.y; suT[2][t] = ru.z; suT[3][t] = ru.w;
    *(float4*)&srs[t][0] = rr;
    #pragma unroll
    for (int r = 0; r < 4; ++r) {
      int ll = (t >> 2) + r * 16;
      int nb = (t & 3) * 4;
      sBT[nb + 0][ll] = rB[r].x; sBT[nb + 1][ll] = rB[r].y;
      sBT[nb + 2][ll] = rB[r].z; sBT[nb + 3][ll] = rB[r].w;
      sCT[nb + 0][ll] = rC[r].x; sCT[nb + 1][ll] = rC[r].y;
      sCT[nb + 2][ll] = rC[r].z; sCT[nb + 3][ll] = rC[r].w;
    }
    if (c0 + CHUNK < L_SEQ) LOAD(c0 + CHUNK);  // prefetch next chunk into regs
    __syncthreads();

    // --- recurrence: 4 steps per float4 batch; only h-fma is serial ---
    #pragma unroll
    for (int g = 0; g < CHUNK; g += 4) {
      float4 dl4 = *(const float4*)&sdT[ch][g];
      float4 ul4 = *(const float4*)&suT[ch][g];
      float4 Bn4 = *(const float4*)&sBT[n][g];
      float4 Cn4 = *(const float4*)&sCT[n][g];
      float dl[4] = {dl4.x, dl4.y, dl4.z, dl4.w};
      float ul[4] = {ul4.x, ul4.y, ul4.z, ul4.w};
      float Bn[4] = {Bn4.x, Bn4.y, Bn4.z, Bn4.w};
      float Cn[4] = {Cn4.x, Cn4.y, Cn4.z, Cn4.w};
      #pragma unroll
      for (int i = 0; i < 4; ++i) {
        float dA = __expf(dl[i] * An);
        h = dA * h + (dl[i] * ul[i]) * Bn[i];
        float vv = h * Cn[i];
        if (n == 0) vv += ul[i] * Dd;   // fold u*D into state-0 slot
        sv[g + i][t] = vv;              // fire-and-forget
      }
    }
    __syncthreads();

    // --- parallel 16-state reduction + SiLU gate ---
    #pragma unroll
    for (int r = 0; r < 4; ++r) {
      int ll = (t >> 2) + r * 16;
      int c2 = t & 3;
      const float4* p = (const float4*)&sv[ll][c2 * 16];
      float4 a = p[0], b = p[1], c = p[2], e = p[3];
      float s = ((a.x + a.y) + (a.z + a.w)) + ((b.x + b.y) + (b.z + b.w))
              + ((c.x + c.y) + (c.z + c.w)) + ((e.x + e.y) + (e.z + e.w));
      float rv = srs[ll][c2];
      float sig = 1.f / (1.f + __expf(-rv));
      sy[ll][c2] = s * (rv * sig);
    }
    __syncthreads();
    *(float4*)&y[(size_t)(c0 + t) * ldy + d0] = *(float4*)&sy[t][0];
  }
}

// ---------------- launch ----------------
extern "C" void kernel_launch(void* const* d_in, const int* in_sizes, int n_in,
                              void* d_out, int out_size, void* d_ws, size_t ws_size,
                              hipStream_t stream)
{
  const float* x      = (const float*)d_in[0];
  const float* W_in   = (const float*)d_in[1];
  const float* W_conv = (const float*)d_in[2];
  const float* b_conv = (const float*)d_in[3];
  const float* W_x    = (const float*)d_in[4];
  const float* W_dt   = (const float*)d_in[5];
  const float* b_dt   = (const float*)d_in[6];
  const float* A_log  = (const float*)d_in[7];
  const float* Dp     = (const float*)d_in[8];
  const float* W_out  = (const float*)d_in[9];
  const float* ln_s   = (const float*)d_in[10];
  const float* ln_b   = (const float*)d_in[11];

  char* ws = (char*)d_ws;
  float* xn    = (float*)(ws);                       // 8 MB
  float* xr    = (float*)(ws + (8u  << 20));         // 32 MB: [u | res] per row
  float* u2    = (float*)(ws + (40u << 20));         // 16 MB
  float* xdbl  = (float*)(ws + (56u << 20));         // 0.75 MB
  float* delta = (float*)(ws + (57u << 20));         // 16 MB
  float* res   = xr + DI;                            // ld = 2*DI
  float* y     = xr;                                 // reuse dead u-columns, ld = 2*DI

  ln_kernel<<<L_SEQ, 256, 0, stream>>>(x, ln_s, ln_b, xn);

  gemm_f32<0><<<dim3((2 * DI) / 64, L_SEQ / 128), 256, 0, stream>>>(
      xn, DM, W_in, 2 * DI, xr, 2 * DI, L_SEQ, 2 * DI, DM, nullptr, nullptr, 0);

  conv_silu_kernel<<<dim3(DI / 256, L_SEQ), 256, 0, stream>>>(xr, W_conv, b_conv, u2);

  xdbl_kernel<<<L_SEQ, 128, 0, stream>>>(u2, W_x, xdbl);

  gemm_f32<1><<<dim3(DI / 64, L_SEQ / 128), 256, 0, stream>>>(
      xdbl, 96, W_dt, DI, delta, DI, L_SEQ, DI, DTR, b_dt, nullptr, 0);

  scan_kernel<<<DI / 4, 64, 0, stream>>>(
      delta, u2, res, 2 * DI, xdbl, A_log, Dp, y, 2 * DI);

  gemm_f32<2><<<dim3(DM / 64, L_SEQ / 128), 256, 0, stream>>>(
      y, 2 * DI, W_out, DM, (float*)d_out, DM, L_SEQ, DM, DI, nullptr, x, DM);
}

// Round 3
// 390.684 us; speedup vs baseline: 2.6498x; 1.5497x over previous
//
#include <hip/hip_runtime.h>
#include <math.h>

#define L_SEQ 2048
#define DM 1024
#define DI 2048
#define DS 16
#define DTR 64
#define EPS 1e-5f

typedef float f32x4 __attribute__((ext_vector_type(4)));
typedef __bf16 bf16x8 __attribute__((ext_vector_type(8)));

static __device__ __forceinline__ unsigned short f2bf(float f) {
  union { float f; unsigned u; } v; v.f = f;
  unsigned r = v.u + 0x7fffu + ((v.u >> 16) & 1u);
  return (unsigned short)(r >> 16);
}

// ---------------- LayerNorm -> bf16 ----------------
__global__ __launch_bounds__(256) void ln_kernel(const float* __restrict__ x,
                                                 const float* __restrict__ sc,
                                                 const float* __restrict__ bi,
                                                 unsigned short* __restrict__ xnb) {
  int row = blockIdx.x;
  int t = threadIdx.x;
  float4 xv = ((const float4*)(x + (size_t)row * DM))[t];
  float s  = xv.x + xv.y + xv.z + xv.w;
  float s2 = xv.x*xv.x + xv.y*xv.y + xv.z*xv.z + xv.w*xv.w;
  #pragma unroll
  for (int m = 32; m >= 1; m >>= 1) {
    s  += __shfl_xor(s, m);
    s2 += __shfl_xor(s2, m);
  }
  __shared__ float red[8];
  int wid = t >> 6, lane = t & 63;
  if (lane == 0) { red[wid] = s; red[4 + wid] = s2; }
  __syncthreads();
  s  = red[0] + red[1] + red[2] + red[3];
  s2 = red[4] + red[5] + red[6] + red[7];
  float mu = s * (1.f / DM);
  float var = s2 * (1.f / DM) - mu * mu;
  float rs = rsqrtf(var + EPS);
  float4 sc4 = ((const float4*)sc)[t];
  float4 bi4 = ((const float4*)bi)[t];
  ushort4 ob;
  ob.x = f2bf((xv.x - mu) * rs * sc4.x + bi4.x);
  ob.y = f2bf((xv.y - mu) * rs * sc4.y + bi4.y);
  ob.z = f2bf((xv.z - mu) * rs * sc4.z + bi4.z);
  ob.w = f2bf((xv.w - mu) * rs * sc4.w + bi4.w);
  *(ushort4*)&xnb[(size_t)row * DM + t * 4] = ob;
}

// ---------------- transpose + fp32->bf16: W[K][N] -> Wt[N][K] ----------------
__global__ __launch_bounds__(256) void trans_bf16(
    const float* __restrict__ W, unsigned short* __restrict__ Wt, int K, int N)
{
  __shared__ unsigned short s[64][80];
  int n0 = blockIdx.x * 64, k0 = blockIdx.y * 64;
  int tid = threadIdx.x;
  #pragma unroll
  for (int p = 0; p < 4; ++p) {
    int i = p * 16 + (tid >> 4);
    int j = (tid & 15) * 4;
    float4 w = *(const float4*)&W[(size_t)(k0 + i) * N + n0 + j];
    s[j + 0][i] = f2bf(w.x); s[j + 1][i] = f2bf(w.y);
    s[j + 2][i] = f2bf(w.z); s[j + 3][i] = f2bf(w.w);
  }
  __syncthreads();
  #pragma unroll
  for (int q = 0; q < 2; ++q) {
    int n = q * 32 + (tid >> 3);
    int i8 = (tid & 7) * 8;
    *(int4*)&Wt[(size_t)(n0 + n) * K + k0 + i8] = *(const int4*)&s[n][i8];
  }
}

// ---------------- bf16 MFMA GEMM: C = A(MxK) @ Bt(NxK)^T ----------------
// 128x128 tile, BK=64, 256 threads = 4 waves (2x2), 4x4 16x16 frags/wave.
// XOR-swizzled LDS (write+read both swizzled), reg-prefetch of next K-tile.
// EPI: 0 = none, 2 = + R[row,col] (fp32 residual)
template<int EPI>
__global__ __launch_bounds__(256) void gemm_bf16(
    const unsigned short* __restrict__ A, int lda,   // bf16 [M][K]
    const unsigned short* __restrict__ Bt, int ldb,  // bf16 [N][K]
    float* __restrict__ C, int ldc,
    int M, int N, int K,
    const float* __restrict__ R, int ldr)
{
  __shared__ __align__(16) char sm[32768];
  char* smA = sm;
  char* smB = sm + 16384;
  int tid = threadIdx.x;
  int lane = tid & 63;
  int wid = tid >> 6;
  int wm = wid >> 1, wn = wid & 1;
  int m0 = blockIdx.y * 128, n0 = blockIdx.x * 128;

  int srow = tid >> 3;            // 0..31
  int scol = (tid & 7) * 8;       // bf16 col
  const unsigned short* pA = A  + (size_t)(m0 + srow) * lda + scol;
  const unsigned short* pB = Bt + (size_t)(n0 + srow) * ldb + scol;
  int wAddr[4];
  #pragma unroll
  for (int p = 0; p < 4; ++p) {
    int r = srow + p * 32;
    wAddr[p] = r * 128 + ((scol * 2) ^ ((r & 7) << 4));
  }

  f32x4 acc[4][4];
  #pragma unroll
  for (int m = 0; m < 4; ++m)
    #pragma unroll
    for (int n = 0; n < 4; ++n) acc[m][n] = (f32x4){0.f, 0.f, 0.f, 0.f};

  int4 ra[4], rb[4];
  int nt = K / 64;
  #pragma unroll
  for (int p = 0; p < 4; ++p) {
    ra[p] = *(const int4*)(pA + (size_t)p * 32 * lda);
    rb[p] = *(const int4*)(pB + (size_t)p * 32 * ldb);
  }

  for (int t = 0; t < nt; ++t) {
    __syncthreads();
    #pragma unroll
    for (int p = 0; p < 4; ++p) {
      *(int4*)(smA + wAddr[p]) = ra[p];
      *(int4*)(smB + wAddr[p]) = rb[p];
    }
    if (t + 1 < nt) {
      const unsigned short* qA = pA + (size_t)(t + 1) * 64;
      const unsigned short* qB = pB + (size_t)(t + 1) * 64;
      #pragma unroll
      for (int p = 0; p < 4; ++p) {
        ra[p] = *(const int4*)(qA + (size_t)p * 32 * lda);
        rb[p] = *(const int4*)(qB + (size_t)p * 32 * ldb);
      }
    }
    __syncthreads();

    bf16x8 aF[2][4], bF[2][4];
    #pragma unroll
    for (int kk = 0; kk < 2; ++kk)
      #pragma unroll
      for (int m = 0; m < 4; ++m) {
        int rA = wm * 64 + m * 16 + (lane & 15);
        int cb = kk * 64 + (lane >> 4) * 16;
        aF[kk][m] = *(const bf16x8*)(smA + rA * 128 + (cb ^ ((rA & 7) << 4)));
        int rB = wn * 64 + m * 16 + (lane & 15);
        bF[kk][m] = *(const bf16x8*)(smB + rB * 128 + (cb ^ ((rB & 7) << 4)));
      }
    #pragma unroll
    for (int kk = 0; kk < 2; ++kk)
      #pragma unroll
      for (int m = 0; m < 4; ++m)
        #pragma unroll
        for (int n = 0; n < 4; ++n)
          acc[m][n] = __builtin_amdgcn_mfma_f32_16x16x32_bf16(
              aF[kk][m], bF[kk][n], acc[m][n], 0, 0, 0);
  }

  int cm = (lane >> 4) * 4;
  int cn = lane & 15;
  #pragma unroll
  for (int m = 0; m < 4; ++m)
    #pragma unroll
    for (int n = 0; n < 4; ++n) {
      int col = n0 + wn * 64 + n * 16 + cn;
      #pragma unroll
      for (int r = 0; r < 4; ++r) {
        int row = m0 + wm * 64 + m * 16 + cm + r;
        float v = acc[m][n][r];
        if (EPI == 2) v += R[(size_t)row * ldr + col];
        C[(size_t)row * ldc + col] = v;
      }
    }
}

// ---------------- Generic fp32 GEMM (kept for GEMM2, K=64) ----------------
template<int EPI>
__global__ __launch_bounds__(256) void gemm_f32(
    const float* __restrict__ A, int lda,
    const float* __restrict__ B, int ldb,
    float* __restrict__ C, int ldc,
    int M, int N, int K,
    const float* __restrict__ bias,
    const float* __restrict__ R, int ldr)
{
  __shared__ __align__(16) float As[16][132];
  __shared__ __align__(16) float Bs[16][64];
  int tid = threadIdx.x;
  int tx = tid & 15, ty = tid >> 4;
  int m0 = blockIdx.y * 128, n0 = blockIdx.x * 64;
  float acc[8][4];
  #pragma unroll
  for (int i = 0; i < 8; ++i)
    #pragma unroll
    for (int j = 0; j < 4; ++j) acc[i][j] = 0.f;

  for (int k0 = 0; k0 < K; k0 += 16) {
    int kk4 = (tid & 3) << 2;
    #pragma unroll
    for (int p = 0; p < 2; ++p) {
      int r = (tid >> 2) + 64 * p;
      float4 av = *(const float4*)&A[(size_t)(m0 + r) * lda + k0 + kk4];
      As[kk4 + 0][r] = av.x;
      As[kk4 + 1][r] = av.y;
      As[kk4 + 2][r] = av.z;
      As[kk4 + 3][r] = av.w;
    }
    int rb = tid >> 4;
    int c4 = (tid & 15) << 2;
    *(float4*)&Bs[rb][c4] = *(const float4*)&B[(size_t)(k0 + rb) * ldb + n0 + c4];
    __syncthreads();
    #pragma unroll
    for (int kk = 0; kk < 16; ++kk) {
      float4 a0 = *(const float4*)&As[kk][ty * 8];
      float4 a1 = *(const float4*)&As[kk][ty * 8 + 4];
      float4 b  = *(const float4*)&Bs[kk][tx * 4];
      float av[8] = {a0.x, a0.y, a0.z, a0.w, a1.x, a1.y, a1.z, a1.w};
      float bv[4] = {b.x, b.y, b.z, b.w};
      #pragma unroll
      for (int i = 0; i < 8; ++i)
        #pragma unroll
        for (int j = 0; j < 4; ++j) acc[i][j] += av[i] * bv[j];
    }
    __syncthreads();
  }

  #pragma unroll
  for (int i = 0; i < 8; ++i) {
    int row = m0 + ty * 8 + i;
    int col = n0 + tx * 4;
    float v[4];
    #pragma unroll
    for (int j = 0; j < 4; ++j) v[j] = acc[i][j];
    if (EPI == 1) {
      #pragma unroll
      for (int j = 0; j < 4; ++j) {
        float w = v[j] + bias[col + j];
        v[j] = (w > 20.f) ? w : log1pf(__expf(w));
      }
    }
    if (EPI == 2) {
      float4 r4 = *(const float4*)&R[(size_t)row * ldr + col];
      v[0] += r4.x; v[1] += r4.y; v[2] += r4.z; v[3] += r4.w;
    }
    float4 o; o.x = v[0]; o.y = v[1]; o.z = v[2]; o.w = v[3];
    *(float4*)&C[(size_t)row * ldc + col] = o;
  }
}

// ---------------- causal conv4 + SiLU ----------------
__global__ __launch_bounds__(256) void conv_silu_kernel(
    const float* __restrict__ xr,  // u = xr[:, :DI], row stride 2*DI
    const float* __restrict__ Wc, const float* __restrict__ bc,
    float* __restrict__ u2)
{
  int d = blockIdx.x * 256 + threadIdx.x;
  int l = blockIdx.y;
  float acc = bc[d];
  #pragma unroll
  for (int k = 0; k < 4; ++k) {
    int ll = l + k - 3;
    if (ll >= 0) acc += xr[(size_t)ll * (2 * DI) + d] * Wc[k * DI + d];
  }
  float sig = 1.f / (1.f + __expf(-acc));
  u2[(size_t)l * DI + d] = acc * sig;
}

// ---------------- x_dbl = u2 @ W_x (K=2048, N=96) ----------------
__global__ __launch_bounds__(128) void xdbl_kernel(
    const float* __restrict__ u2, const float* __restrict__ Wx,
    float* __restrict__ xdbl)
{
  __shared__ float srow[DI];
  int l = blockIdx.x;
  for (int i = threadIdx.x; i < DI / 4; i += 128)
    ((float4*)srow)[i] = ((const float4*)(u2 + (size_t)l * DI))[i];
  __syncthreads();
  int j = threadIdx.x;
  if (j < 96) {
    float acc = 0.f;
    #pragma unroll 8
    for (int k = 0; k < DI; ++k) acc += srow[k] * Wx[k * 96 + j];
    xdbl[(size_t)l * 96 + j] = acc;
  }
}

// ---------------- selective scan (ILP-restructured, y -> bf16) ----------------
#define CHUNK 64
__global__ __launch_bounds__(64) void scan_kernel(
    const float* __restrict__ delta, const float* __restrict__ u2,
    const float* __restrict__ res, int ldres,
    const float* __restrict__ xdbl,
    const float* __restrict__ A_log, const float* __restrict__ Dp,
    unsigned short* __restrict__ yb, int ldyu)
{
  int t = threadIdx.x;
  int ch = t >> 4;
  int n  = t & 15;
  int d0 = blockIdx.x * 4;
  int d  = d0 + ch;

  __shared__ __align__(16) float sdT[4][68], suT[4][68];
  __shared__ __align__(16) float sBT[16][68], sCT[16][68];
  __shared__ __align__(16) float srs[CHUNK][4];
  __shared__ __align__(16) float sv[CHUNK][68];
  __shared__ __align__(16) float sy[CHUNK][4];

  float An = -__expf(A_log[d * DS + n]);
  float Dd = Dp[d];
  float h = 0.f;

  float4 rd, ru, rr, rB[4], rC[4];
  auto LOAD = [&](int c0) {
    int l = c0 + t;
    rd = *(const float4*)&delta[(size_t)l * DI + d0];
    ru = *(const float4*)&u2[(size_t)l * DI + d0];
    rr = *(const float4*)&res[(size_t)l * ldres + d0];
    #pragma unroll
    for (int r = 0; r < 4; ++r) {
      int ll = c0 + (t >> 2) + r * 16;
      int n4 = (t & 3) * 4;
      rB[r] = *(const float4*)&xdbl[(size_t)ll * 96 + 64 + n4];
      rC[r] = *(const float4*)&xdbl[(size_t)ll * 96 + 80 + n4];
    }
  };

  LOAD(0);
  for (int c0 = 0; c0 < L_SEQ; c0 += CHUNK) {
    __syncthreads();
    sdT[0][t] = rd.x; sdT[1][t] = rd.y; sdT[2][t] = rd.z; sdT[3][t] = rd.w;
    suT[0][t] = ru.x; suT[1][t] = ru.y; suT[2][t] = ru.z; suT[3][t] = ru.w;
    *(float4*)&srs[t][0] = rr;
    #pragma unroll
    for (int r = 0; r < 4; ++r) {
      int ll = (t >> 2) + r * 16;
      int nb = (t & 3) * 4;
      sBT[nb + 0][ll] = rB[r].x; sBT[nb + 1][ll] = rB[r].y;
      sBT[nb + 2][ll] = rB[r].z; sBT[nb + 3][ll] = rB[r].w;
      sCT[nb + 0][ll] = rC[r].x; sCT[nb + 1][ll] = rC[r].y;
      sCT[nb + 2][ll] = rC[r].z; sCT[nb + 3][ll] = rC[r].w;
    }
    if (c0 + CHUNK < L_SEQ) LOAD(c0 + CHUNK);
    __syncthreads();

    #pragma unroll
    for (int g = 0; g < CHUNK; g += 4) {
      float4 dl4 = *(const float4*)&sdT[ch][g];
      float4 ul4 = *(const float4*)&suT[ch][g];
      float4 Bn4 = *(const float4*)&sBT[n][g];
      float4 Cn4 = *(const float4*)&sCT[n][g];
      float dl[4] = {dl4.x, dl4.y, dl4.z, dl4.w};
      float ul[4] = {ul4.x, ul4.y, ul4.z, ul4.w};
      float Bn[4] = {Bn4.x, Bn4.y, Bn4.z, Bn4.w};
      float Cn[4] = {Cn4.x, Cn4.y, Cn4.z, Cn4.w};
      #pragma unroll
      for (int i = 0; i < 4; ++i) {
        float dA = __expf(dl[i] * An);
        h = dA * h + (dl[i] * ul[i]) * Bn[i];
        float vv = h * Cn[i];
        if (n == 0) vv += ul[i] * Dd;
        sv[g + i][t] = vv;
      }
    }
    __syncthreads();

    #pragma unroll
    for (int r = 0; r < 4; ++r) {
      int ll = (t >> 2) + r * 16;
      int c2 = t & 3;
      const float4* p = (const float4*)&sv[ll][c2 * 16];
      float4 a = p[0], b = p[1], c = p[2], e = p[3];
      float s = ((a.x + a.y) + (a.z + a.w)) + ((b.x + b.y) + (b.z + b.w))
              + ((c.x + c.y) + (c.z + c.w)) + ((e.x + e.y) + (e.z + e.w));
      float rv = srs[ll][c2];
      float sig = 1.f / (1.f + __expf(-rv));
      sy[ll][c2] = s * (rv * sig);
    }
    __syncthreads();
    float4 v = *(const float4*)&sy[t][0];
    ushort4 ob;
    ob.x = f2bf(v.x); ob.y = f2bf(v.y); ob.z = f2bf(v.z); ob.w = f2bf(v.w);
    *(ushort4*)&yb[(size_t)(c0 + t) * ldyu + d0] = ob;
  }
}

// ---------------- launch ----------------
extern "C" void kernel_launch(void* const* d_in, const int* in_sizes, int n_in,
                              void* d_out, int out_size, void* d_ws, size_t ws_size,
                              hipStream_t stream)
{
  const float* x      = (const float*)d_in[0];
  const float* W_in   = (const float*)d_in[1];
  const float* W_conv = (const float*)d_in[2];
  const float* b_conv = (const float*)d_in[3];
  const float* W_x    = (const float*)d_in[4];
  const float* W_dt   = (const float*)d_in[5];
  const float* b_dt   = (const float*)d_in[6];
  const float* A_log  = (const float*)d_in[7];
  const float* Dp     = (const float*)d_in[8];
  const float* W_out  = (const float*)d_in[9];
  const float* ln_s   = (const float*)d_in[10];
  const float* ln_b   = (const float*)d_in[11];

  char* ws = (char*)d_ws;
  unsigned short* xnb  = (unsigned short*)ws;            // 4 MB bf16 [2048][1024]
  float* xr    = (float*)(ws + (4u  << 20));             // 32 MB fp32 [2048][4096] = [u|res]
  float* u2    = (float*)(ws + (36u << 20));             // 16 MB
  float* xdbl  = (float*)(ws + (52u << 20));             // 0.75 MB
  float* delta = (float*)(ws + (53u << 20));             // 16 MB (ends at 69 MB)
  unsigned short* Wtin  = (unsigned short*)(ws + (53u << 20)); // 8 MB, aliases delta (dead before GEMM2)
  unsigned short* Wtout = (unsigned short*)ws;                 // 4 MB, aliases xnb (dead after GEMM1)
  float* res   = xr + DI;                                // ld = 2*DI
  unsigned short* yb = (unsigned short*)xr;              // bf16 y in dead u-cols, ld = 4*DI ushorts

  ln_kernel<<<L_SEQ, 256, 0, stream>>>(x, ln_s, ln_b, xnb);

  trans_bf16<<<dim3((2 * DI) / 64, DM / 64), 256, 0, stream>>>(W_in, Wtin, DM, 2 * DI);

  gemm_bf16<0><<<dim3((2 * DI) / 128, L_SEQ / 128), 256, 0, stream>>>(
      xnb, DM, Wtin, DM, xr, 2 * DI, L_SEQ, 2 * DI, DM, nullptr, 0);

  conv_silu_kernel<<<dim3(DI / 256, L_SEQ), 256, 0, stream>>>(xr, W_conv, b_conv, u2);

  trans_bf16<<<dim3(DM / 64, DI / 64), 256, 0, stream>>>(W_out, Wtout, DI, DM);

  xdbl_kernel<<<L_SEQ, 128, 0, stream>>>(u2, W_x, xdbl);

  gemm_f32<1><<<dim3(DI / 64, L_SEQ / 128), 256, 0, stream>>>(
      xdbl, 96, W_dt, DI, delta, DI, L_SEQ, DI, DTR, b_dt, nullptr, 0);

  scan_kernel<<<DI / 4, 64, 0, stream>>>(
      delta, u2, res, 2 * DI, xdbl, A_log, Dp, yb, 4 * DI);

  gemm_bf16<2><<<dim3(DM / 128, L_SEQ / 128), 256, 0, stream>>>(
      yb, 4 * DI, Wtout, DI, (float*)d_out, DM, L_SEQ, DM, DI, x, DM);
}